// Round 7
// baseline (254.838 us; speedup 1.0000x reference)
//
#include <hip/hip_runtime.h>
#include <math.h>

typedef _Float16 half8 __attribute__((ext_vector_type(8)));
typedef __fp16 fp16x2 __attribute__((ext_vector_type(2)));
typedef float floatx4 __attribute__((ext_vector_type(4)));
typedef float floatx2 __attribute__((ext_vector_type(2)));

constexpr int IN_DIM = 36;
constexpr int BLOCKS = 2048;
// Channel map of zxbcdt (152 + pad to 160): z 0..63 (tiles 0-3), xh 64..127
// (tiles 4-7), B 128..135 / C 136..143 (tile 8), dt 144..151 (tile 9 lanes q<2).

__device__ __forceinline__ float fast_rcp(float v) { return __builtin_amdgcn_rcpf(v); }
__device__ __forceinline__ float silu_f(float v) { return v * fast_rcp(1.0f + __expf(-v)); }
__device__ __forceinline__ float softplus_f(float v) {
    return fmaxf(v, 0.0f) + __logf(1.0f + __expf(-fabsf(v)));
}
__device__ __forceinline__ float pk2f(float a, float b) {
    fp16x2 p = __builtin_amdgcn_cvt_pkrtz(a, b);   // v_cvt_pkrtz_f16_f32
    return __builtin_bit_cast(float, p);
}

// ---- prep: 24 fp16 A-operand fragments into d_ws (one block per fragment) ----
// fid 0..19: GEMM1 A = Wc^T (Wc[k][ch] = sum_m f_out_w[m][k]*in_proj_w[ch][m],
//   conv_w folded for ch in [64,144)). Ghost k=36 carries the fully-fused bias.
// fid 20..23: GEMM2 A = out_proj_w[m][k] * norm_w[k] (norm fold).
extern "C" __global__ void __launch_bounds__(64)
prep_kernel(const float* __restrict__ f_out_w, const float* __restrict__ f_out_b,
            const float* __restrict__ in_proj_w, const float* __restrict__ conv_w,
            const float* __restrict__ conv_b, const float* __restrict__ dt_bias,
            const float* __restrict__ norm_w, const float* __restrict__ out_proj_w,
            void* __restrict__ ws) {
    const int fid = blockIdx.x;
    const int L = threadIdx.x;
    const int c = L & 15, q = L >> 4;
    unsigned short* fr = (unsigned short*)ws;
    for (int j = 0; j < 8; ++j) {
        float val = 0.f;
        if (fid < 20) {
            const int t = fid >> 1, ks = fid & 1;
            const int m = t * 16 + c;               // proj channel
            const int k = ks * 32 + q * 8 + j;      // feature
            if (m < 152) {
                if (k < IN_DIM) {
                    float acc = 0.f;
                    for (int mm = 0; mm < 32; ++mm)
                        acc += f_out_w[mm * IN_DIM + k] * in_proj_w[m * 32 + mm];
                    if (m >= 64 && m < 144) acc *= conv_w[(m - 64) * 2 + 1];
                    val = acc;
                } else if (k == IN_DIM) {           // ghost-feature bias slot
                    float acc = 0.f;
                    for (int mm = 0; mm < 32; ++mm)
                        acc += f_out_b[mm] * in_proj_w[m * 32 + mm];
                    if (m >= 64 && m < 144)      val = acc * conv_w[(m - 64) * 2 + 1] + conv_b[m - 64];
                    else if (m >= 144)           val = acc + dt_bias[m - 144];
                    else                         val = acc;
                }
            }
        } else {
            const int mt = (fid - 20) >> 1, ks = (fid - 20) & 1;
            const int m = mt * 16 + c;              // out channel (<32)
            const int k = ks * 32 + q * 8 + j;      // y channel (<64)
            val = out_proj_w[m * 64 + k] * norm_w[k];
        }
        _Float16 h = (_Float16)val;
        fr[fid * 512 + L * 8 + j] = __builtin_bit_cast(unsigned short, h);
    }
}

// ---- main: transposed GEMMs; lane (c,q) owns row c of its 16-row tile ----
// R14 = R13 + double-pump: two row-tiles (A,B) processed per iteration so
// every weight fragment is ds_read ONCE per pair instead of once per tile
// (24 -> 12 b128 reads/tile on the DS pipe), and every serial phase
// (bc reduce, scale broadcast, exp chain, softmax reduce) has a second
// independent instance to interleave with (the R13 chain alternated
// VALU<->DS serially; dual tiles let the pipes overlap).
// Register budget: peak ~135 < 170 @ (256,3) — no forced cap (both (256,4)
// attempts spilled; occupancy is pinned ~3 waves/SIMD regardless, R13).
// Spill tripwire: FETCH ~37MB / WRITE ~65.5MB must not move.
extern "C" __global__ void __launch_bounds__(256, 3)
mamba_mfma_kernel(const float* __restrict__ x,
                  const float* __restrict__ D_skip,
                  const void* __restrict__ ws,
                  float* __restrict__ out,
                  int tiles_per_wave) {
    __shared__ float4 ldsW[1536];                  // 24 KiB: 24 A-fragments, 16B-aligned
    __shared__ __align__(16) _Float16 ldsY[4][2][16 * 72];  // per-wave, per-subtile y
    const int lane = threadIdx.x & 63;
    const int wv   = threadIdx.x >> 6;
    const int c = lane & 15, q = lane >> 4;

    // cooperative stage of all 24 fragments: 24576 B / 256 thr = 6 float4 each
    {
        const float4* src = (const float4*)ws;
#pragma unroll
        for (int i = 0; i < 6; ++i)
            ldsW[threadIdx.x + 256 * i] = src[threadIdx.x + 256 * i];
    }

    const float4 dskv = *(const float4*)(D_skip + (q & 1) * 4);  // heads 4(q&1)+r
    _Float16* myLA = ldsY[wv][0];
    _Float16* myLB = ldsY[wv][1];

    const long rowBase = (long)(blockIdx.x * 4 + wv) * tiles_per_wave * 16;
    const float* xrow = x + (rowBase + c) * (long)IN_DIM;
    const float4 zf4 = make_float4(0.f, 0.f, 0.f, 0.f);

    // pair 0 x loads (tileA = 0, tileB = 1)
    float4 xaA, xbA, xctA, xaB, xbB, xctB;
    {
        const float* pA = xrow;
        const float* pB = xrow + 16 * IN_DIM;
        xaA = *(const float4*)(pA + q * 8);
        xbA = *(const float4*)(pA + q * 8 + 4);
        xctA = (q == 0) ? *(const float4*)(pA + 32) : zf4;
        xaB = *(const float4*)(pB + q * 8);
        xbB = *(const float4*)(pB + q * 8 + 4);
        xctB = (q == 0) ? *(const float4*)(pB + 32) : zf4;
    }

    __syncthreads();                               // weights resident in LDS
    const char* Wb = (const char*)ldsW;
    auto ldW = [&](int fid) {
        return *(const half8*)(Wb + (size_t)(fid * 64 + lane) * 16);
    };
    auto packBx = [&](const float4 fxa, const float4 fxb, const float4 fxct,
                      half8& B0, half8& B1) {
        float4 t0, t1;
        t0.x = pk2f(fxa.x, fxa.y);
        t0.y = pk2f(fxa.z, fxa.w);
        t0.z = pk2f(fxb.x, fxb.y);
        t0.w = pk2f(fxb.z, fxb.w);
        t1.x = pk2f(fxct.x, fxct.y);                // fxct already 0 for q!=0
        t1.y = pk2f(fxct.z, fxct.w);
        t1.z = (q == 0) ? pk2f(1.0f, 0.0f) : 0.0f;  // ghost feature -> bias
        t1.w = 0.0f;
        B0 = __builtin_bit_cast(half8, t0);
        B1 = __builtin_bit_cast(half8, t1);
    };

    const int npairs = tiles_per_wave >> 1;        // tiles_per_wave == 4 -> 2
    const floatx4 z4 = {0.f, 0.f, 0.f, 0.f};

#pragma unroll 1
    for (int pr = 0; pr < npairs; ++pr) {
        // prefetch next pair's x (branchless clamp; harmless re-read on last)
        const int pn = (pr + 1 < npairs) ? pr + 1 : pr;
        const float* pA = xrow + (size_t)(pn * 2) * 16 * IN_DIM;
        const float* pB = pA + 16 * IN_DIM;
        const float4 naA = *(const float4*)(pA + q * 8);
        const float4 nbA = *(const float4*)(pA + q * 8 + 4);
        const float4 ncA = (q == 0) ? *(const float4*)(pA + 32) : zf4;
        const float4 naB = *(const float4*)(pB + q * 8);
        const float4 nbB = *(const float4*)(pB + q * 8 + 4);
        const float4 ncB = (q == 0) ? *(const float4*)(pB + 32) : zf4;

        half8 BxA0, BxA1, BxB0, BxB1;
        packBx(xaA, xbA, xctA, BxA0, BxA1);
        packBx(xaB, xbB, xctB, BxB0, BxB1);

        // ---- tiles 8 (B/C) and 9 (dt): weights read once, used for A and B ----
        floatx4 acc8A, acc9A, acc8B, acc9B;
        {
            const half8 c80 = ldW(16), c81 = ldW(17);
            const half8 c90 = ldW(18), c91 = ldW(19);
            acc8A = __builtin_amdgcn_mfma_f32_16x16x32_f16(c80, BxA0, z4, 0, 0, 0);
            acc8B = __builtin_amdgcn_mfma_f32_16x16x32_f16(c80, BxB0, z4, 0, 0, 0);
            acc8A = __builtin_amdgcn_mfma_f32_16x16x32_f16(c81, BxA1, acc8A, 0, 0, 0);
            acc8B = __builtin_amdgcn_mfma_f32_16x16x32_f16(c81, BxB1, acc8B, 0, 0, 0);
            acc9A = __builtin_amdgcn_mfma_f32_16x16x32_f16(c90, BxA0, z4, 0, 0, 0);
            acc9B = __builtin_amdgcn_mfma_f32_16x16x32_f16(c90, BxB0, z4, 0, 0, 0);
            acc9A = __builtin_amdgcn_mfma_f32_16x16x32_f16(c91, BxA1, acc9A, 0, 0, 0);
            acc9B = __builtin_amdgcn_mfma_f32_16x16x32_f16(c91, BxB1, acc9B, 0, 0, 0);
        }

        // conv+silu on B/C (both tiles — independent chains interleave)
#pragma unroll
        for (int r = 0; r < 4; ++r) acc8A[r] = silu_f(acc8A[r]);
#pragma unroll
        for (int r = 0; r < 4; ++r) acc8B[r] = silu_f(acc8B[r]);

        // bc reduce: xor32 pairs, in-lane dot, xor16 combine (A and B in parallel)
        float partA = 0.f, partB = 0.f;
#pragma unroll
        for (int r = 0; r < 4; ++r) {
            const float rvA = __shfl_xor(acc8A[r], 32, 64);
            const float rvB = __shfl_xor(acc8B[r], 32, 64);
            partA = __builtin_fmaf(acc8A[r], rvA, partA);
            partB = __builtin_fmaf(acc8B[r], rvB, partB);
        }
        const float bcA = partA + __shfl_xor(partA, 16, 64);
        const float bcB = partB + __shfl_xor(partB, 16, 64);

        // per-head scale + broadcast from lanes (c,0)/(c,1)
        float sclAA[4], sclAB[4];
        {
            float scaleA[4], scaleB[4];
#pragma unroll
            for (int r = 0; r < 4; ++r) {
                scaleA[r] = __builtin_fmaf(softplus_f(acc9A[r]), bcA, dskv[r]);
                scaleB[r] = __builtin_fmaf(softplus_f(acc9B[r]), bcB, dskv[r]);
            }
            float s0A[4], s1A[4], s0B[4], s1B[4];
#pragma unroll
            for (int r = 0; r < 4; ++r) {
                s0A[r] = __shfl(scaleA[r], c, 64);
                s1A[r] = __shfl(scaleA[r], c + 16, 64);
                s0B[r] = __shfl(scaleB[r], c, 64);
                s1B[r] = __shfl(scaleB[r], c + 16, 64);
            }
            const bool hb = (q >= 2);              // head parity for this lane's channels
            sclAA[0] = hb ? s0A[1] : s0A[0];
            sclAA[1] = hb ? s0A[3] : s0A[2];
            sclAA[2] = hb ? s1A[1] : s1A[0];
            sclAA[3] = hb ? s1A[3] : s1A[2];
            sclAB[0] = hb ? s0B[1] : s0B[0];
            sclAB[1] = hb ? s0B[3] : s0B[2];
            sclAB[2] = hb ? s1B[1] : s1B[0];
            sclAB[3] = hb ? s1B[3] : s1B[2];
        }

        // ---- z/xh pairs: weights read once, 8 MFMAs (A+B), consume, discard ----
        floatx2 ypA[4], ypB[4];
        float ssumA = 0.f, ssumB = 0.f;
#pragma unroll
        for (int t = 0; t < 4; ++t) {
            const half8 cz0 = ldW(t * 2 + 0), cz1 = ldW(t * 2 + 1);
            const half8 cx0 = ldW((t + 4) * 2 + 0), cx1 = ldW((t + 4) * 2 + 1);
            floatx4 azA = __builtin_amdgcn_mfma_f32_16x16x32_f16(cz0, BxA0, z4, 0, 0, 0);
            floatx4 azB = __builtin_amdgcn_mfma_f32_16x16x32_f16(cz0, BxB0, z4, 0, 0, 0);
            azA = __builtin_amdgcn_mfma_f32_16x16x32_f16(cz1, BxA1, azA, 0, 0, 0);
            azB = __builtin_amdgcn_mfma_f32_16x16x32_f16(cz1, BxB1, azB, 0, 0, 0);
            floatx4 axA = __builtin_amdgcn_mfma_f32_16x16x32_f16(cx0, BxA0, z4, 0, 0, 0);
            floatx4 axB = __builtin_amdgcn_mfma_f32_16x16x32_f16(cx0, BxB0, z4, 0, 0, 0);
            axA = __builtin_amdgcn_mfma_f32_16x16x32_f16(cx1, BxA1, axA, 0, 0, 0);
            axB = __builtin_amdgcn_mfma_f32_16x16x32_f16(cx1, BxB1, axB, 0, 0, 0);

            float vA[4], vB[4];
#pragma unroll
            for (int r = 0; r < 4; ++r) {
                const float zrA = azA[r], xhA = axA[r];
                const float zrB = azB[r], xhB = axB[r];
                const float denA = (1.0f + __expf(-zrA)) * (1.0f + __expf(-xhA));
                const float denB = (1.0f + __expf(-zrB)) * (1.0f + __expf(-xhB));
                vA[r] = zrA * xhA * sclAA[t] * fast_rcp(denA);
                vB[r] = zrB * xhB * sclAB[t] * fast_rcp(denB);
                ssumA = __builtin_fmaf(vA[r], vA[r], ssumA);
                ssumB = __builtin_fmaf(vB[r], vB[r], ssumB);
            }
            ypA[t].x = pk2f(vA[0], vA[1]);
            ypA[t].y = pk2f(vA[2], vA[3]);
            ypB[t].x = pk2f(vB[0], vB[1]);
            ypB[t].y = pk2f(vB[2], vB[3]);
        }
        ssumA += __shfl_xor(ssumA, 16, 64);
        ssumB += __shfl_xor(ssumB, 16, 64);
        ssumA += __shfl_xor(ssumA, 32, 64);
        ssumB += __shfl_xor(ssumB, 32, 64);
        const float rsA = __builtin_amdgcn_rsqf(__builtin_fmaf(ssumA, 1.0f / 64.0f, 1e-5f));
        const float rsB = __builtin_amdgcn_rsqf(__builtin_fmaf(ssumB, 1.0f / 64.0f, 1e-5f));

        // y -> LDS (half, stride 72) -> B-operands; two buffers so the writes
        // and reads of A and B interleave without aliasing
#pragma unroll
        for (int t = 0; t < 4; ++t) {
            *(floatx2*)(myLA + c * 72 + 16 * t + 4 * q) = ypA[t];   // 8B-aligned
            *(floatx2*)(myLB + c * 72 + 16 * t + 4 * q) = ypB[t];
        }
        const half8 ByA0 = *(const half8*)(myLA + c * 72 + 8 * q);
        const half8 ByA1 = *(const half8*)(myLA + c * 72 + 32 + 8 * q);
        const half8 ByB0 = *(const half8*)(myLB + c * 72 + 8 * q);
        const half8 ByB1 = *(const half8*)(myLB + c * 72 + 32 + 8 * q);

        // GEMM2: A-fragments read once, used for both tiles
        const half8 A300 = ldW(20), A301 = ldW(21);
        const half8 A310 = ldW(22), A311 = ldW(23);

        floatx4 lgA0 = __builtin_amdgcn_mfma_f32_16x16x32_f16(A300, ByA0, z4, 0, 0, 0);
        floatx4 lgB0 = __builtin_amdgcn_mfma_f32_16x16x32_f16(A300, ByB0, z4, 0, 0, 0);
        lgA0 = __builtin_amdgcn_mfma_f32_16x16x32_f16(A301, ByA1, lgA0, 0, 0, 0);
        lgB0 = __builtin_amdgcn_mfma_f32_16x16x32_f16(A301, ByB1, lgB0, 0, 0, 0);
        floatx4 lgA1 = __builtin_amdgcn_mfma_f32_16x16x32_f16(A310, ByA0, z4, 0, 0, 0);
        floatx4 lgB1 = __builtin_amdgcn_mfma_f32_16x16x32_f16(A310, ByB0, z4, 0, 0, 0);
        lgA1 = __builtin_amdgcn_mfma_f32_16x16x32_f16(A311, ByA1, lgA1, 0, 0, 0);
        lgB1 = __builtin_amdgcn_mfma_f32_16x16x32_f16(A311, ByB1, lgB1, 0, 0, 0);

        // softmax over 32 out-chs (both tiles); max-pass skipped (fp32-safe);
        // log2e folded into rs so each exp is a single v_exp_f32 after one mul.
        const float rsA2 = rsA * 1.44269504f;
        const float rsB2 = rsB * 1.44269504f;
        float e0A[4], e1A[4], e0B[4], e1B[4];
        float lsumA = 0.f, lsumB = 0.f;
#pragma unroll
        for (int r = 0; r < 4; ++r) {
            e0A[r] = __builtin_amdgcn_exp2f(lgA0[r] * rsA2);
            e1A[r] = __builtin_amdgcn_exp2f(lgA1[r] * rsA2);
            e0B[r] = __builtin_amdgcn_exp2f(lgB0[r] * rsB2);
            e1B[r] = __builtin_amdgcn_exp2f(lgB1[r] * rsB2);
            lsumA += e0A[r] + e1A[r];
            lsumB += e0B[r] + e1B[r];
        }
        lsumA += __shfl_xor(lsumA, 16, 64);
        lsumB += __shfl_xor(lsumB, 16, 64);
        lsumA += __shfl_xor(lsumA, 32, 64);
        lsumB += __shfl_xor(lsumB, 32, 64);
        const float invA = fast_rcp(lsumA);
        const float invB = fast_rcp(lsumB);

        const long orowA = rowBase + (long)(pr * 2) * 16 + c;
        const long orowB = orowA + 16;
        *(float4*)(out + orowA * 32 + 4 * q) =
            make_float4(e0A[0] * invA, e0A[1] * invA, e0A[2] * invA, e0A[3] * invA);
        *(float4*)(out + orowA * 32 + 16 + 4 * q) =
            make_float4(e1A[0] * invA, e1A[1] * invA, e1A[2] * invA, e1A[3] * invA);
        *(float4*)(out + orowB * 32 + 4 * q) =
            make_float4(e0B[0] * invB, e0B[1] * invB, e0B[2] * invB, e0B[3] * invB);
        *(float4*)(out + orowB * 32 + 16 + 4 * q) =
            make_float4(e1B[0] * invB, e1B[1] * invB, e1B[2] * invB, e1B[3] * invB);

        xaA = naA; xbA = nbA; xctA = ncA;
        xaB = naB; xbB = nbB; xctB = ncB;
    }
}

extern "C" void kernel_launch(void* const* d_in, const int* in_sizes, int n_in,
                              void* d_out, int out_size, void* d_ws, size_t ws_size,
                              hipStream_t stream) {
    const float* x          = (const float*)d_in[0];
    const float* f_out_w    = (const float*)d_in[1];
    const float* f_out_b    = (const float*)d_in[2];
    const float* in_proj_w  = (const float*)d_in[3];
    const float* conv_w     = (const float*)d_in[4];
    const float* conv_b     = (const float*)d_in[5];
    const float* dt_bias    = (const float*)d_in[6];
    // d_in[7] = A_log — unused by the reference
    const float* D_skip     = (const float*)d_in[8];
    const float* norm_w     = (const float*)d_in[9];
    const float* out_proj_w = (const float*)d_in[10];
    float* out = (float*)d_out;

    const int n = in_sizes[0] / IN_DIM;                 // 524288
    const int tiles_per_wave = n / (BLOCKS * 4 * 16);   // 4 (even: pair loop)

    hipLaunchKernelGGL(prep_kernel, dim3(24), dim3(64), 0, stream,
                       f_out_w, f_out_b, in_proj_w, conv_w, conv_b, dt_bias,
                       norm_w, out_proj_w, d_ws);
    hipLaunchKernelGGL(mamba_mfma_kernel, dim3(BLOCKS), dim3(256), 0, stream,
                       x, D_skip, d_ws, out, tiles_per_wave);
}

// Round 8
// 156.558 us; speedup vs baseline: 1.6278x; 1.6278x over previous
//
#include <hip/hip_runtime.h>
#include <math.h>

typedef _Float16 half8 __attribute__((ext_vector_type(8)));
typedef __fp16 fp16x2 __attribute__((ext_vector_type(2)));
typedef float floatx4 __attribute__((ext_vector_type(4)));
typedef float floatx2 __attribute__((ext_vector_type(2)));

constexpr int IN_DIM = 36;
constexpr int BLOCKS = 2048;
// Channel map of zxbcdt (152 + pad to 160): z 0..63 (tiles 0-3), xh 64..127
// (tiles 4-7). R15 remaps tiles 8/9 at prep time so reductions are lane-local:
//   tile 8 slot 4q+r = B[2q+(r>>1)] (r even) / C[2q+(r>>1)] (r odd)
//   tile 9 slot 4q+r = dt[2r + (q>>1)]   (each head duplicated per q-pair)

__device__ __forceinline__ float fast_rcp(float v) { return __builtin_amdgcn_rcpf(v); }
__device__ __forceinline__ float silu_f(float v) { return v * fast_rcp(1.0f + __expf(-v)); }
__device__ __forceinline__ float softplus_f(float v) {
    return fmaxf(v, 0.0f) + __logf(1.0f + __expf(-fabsf(v)));
}
__device__ __forceinline__ float pk2f(float a, float b) {
    fp16x2 p = __builtin_amdgcn_cvt_pkrtz(a, b);   // v_cvt_pkrtz_f16_f32
    return __builtin_bit_cast(float, p);
}

// ---- prep: 24 fp16 A-operand fragments into d_ws (one block per fragment) ----
// fid 0..19: GEMM1 A = Wc^T (Wc[k][ch] = sum_m f_out_w[m][k]*in_proj_w[ch][m],
//   conv_w folded for ch in [64,144)). Ghost k=36 carries the fully-fused bias.
// fid 20..23: GEMM2 A = out_proj_w[m][k] * norm_w[k] (norm fold).
// R15: tiles 8/9 use remapped source channels (see channel map above) so the
// main kernel's bc product and head-scales are lane-local (no broadcasts).
extern "C" __global__ void __launch_bounds__(64)
prep_kernel(const float* __restrict__ f_out_w, const float* __restrict__ f_out_b,
            const float* __restrict__ in_proj_w, const float* __restrict__ conv_w,
            const float* __restrict__ conv_b, const float* __restrict__ dt_bias,
            const float* __restrict__ norm_w, const float* __restrict__ out_proj_w,
            void* __restrict__ ws) {
    const int fid = blockIdx.x;
    const int L = threadIdx.x;
    const int c = L & 15, q = L >> 4;
    unsigned short* fr = (unsigned short*)ws;
    for (int j = 0; j < 8; ++j) {
        float val = 0.f;
        if (fid < 20) {
            const int t = fid >> 1, ks = fid & 1;
            int m = t * 16 + c;                     // source proj channel
            if (t == 8) {                           // B/C interleave remap
                m = ((c & 1) ? 136 : 128) + 2 * (c >> 2) + ((c >> 1) & 1);
            } else if (t == 9) {                    // dt head-duplication remap
                m = 144 + 2 * (c & 3) + (c >> 3);
            }
            const int k = ks * 32 + q * 8 + j;      // feature
            if (m < 152) {
                if (k < IN_DIM) {
                    float acc = 0.f;
                    for (int mm = 0; mm < 32; ++mm)
                        acc += f_out_w[mm * IN_DIM + k] * in_proj_w[m * 32 + mm];
                    if (m >= 64 && m < 144) acc *= conv_w[(m - 64) * 2 + 1];
                    val = acc;
                } else if (k == IN_DIM) {           // ghost-feature bias slot
                    float acc = 0.f;
                    for (int mm = 0; mm < 32; ++mm)
                        acc += f_out_b[mm] * in_proj_w[m * 32 + mm];
                    if (m >= 64 && m < 144)      val = acc * conv_w[(m - 64) * 2 + 1] + conv_b[m - 64];
                    else if (m >= 144)           val = acc + dt_bias[m - 144];
                    else                         val = acc;
                }
            }
        } else {
            const int mt = (fid - 20) >> 1, ks = (fid - 20) & 1;
            const int m = mt * 16 + c;              // out channel (<32)
            const int k = ks * 32 + q * 8 + j;      // y channel (<64)
            val = out_proj_w[m * 64 + k] * norm_w[k];
        }
        _Float16 h = (_Float16)val;
        fr[fid * 512 + L * 8 + j] = __builtin_bit_cast(unsigned short, h);
    }
}

// ---- main: transposed GEMMs; lane (c,q) owns row c of its 16-row tile ----
// R15 = R13 (proven 45.4us; R14's double-pump spilled and is reverted) with
// ONE change: lane-local reductions via the prep-side remap of tiles 8/9.
//   - bc: in-lane products acc8[0]*acc8[1] + acc8[2]*acc8[3], then 2 shuffles
//     (xor16, xor32) instead of 5.
//   - head scales: computed locally in EVERY lane from acc9[t] (head 2t+hb);
//     the 8-shuffle broadcast is deleted.
// Shuffles/tile: 17 -> 6; two serial ds_bpermute round-trips leave the chain;
// no new live state (spill cliff respected — R10/R12/R14 lesson).
extern "C" __global__ void __launch_bounds__(256, 3)
mamba_mfma_kernel(const float* __restrict__ x,
                  const float* __restrict__ D_skip,
                  const void* __restrict__ ws,
                  float* __restrict__ out,
                  int tiles_per_wave) {
    __shared__ float4 ldsW[1536];                  // 24 KiB: 24 A-fragments, 16B-aligned
    __shared__ __align__(16) _Float16 ldsY[4][16 * 72];  // per-wave y buffer, stride 72
    const int lane = threadIdx.x & 63;
    const int wv   = threadIdx.x >> 6;
    const int c = lane & 15, q = lane >> 4;
    const int hb = q >> 1;                         // head parity for this lane

    // cooperative stage of all 24 fragments: 24576 B / 256 thr = 6 float4 each
    {
        const float4* src = (const float4*)ws;
#pragma unroll
        for (int i = 0; i < 6; ++i)
            ldsW[threadIdx.x + 256 * i] = src[threadIdx.x + 256 * i];
    }

    // D_skip for heads {2t+hb}: per-lane scalar loads (once, L3-resident)
    float dsk[4];
#pragma unroll
    for (int t = 0; t < 4; ++t) dsk[t] = D_skip[2 * t + hb];

    _Float16* myL = ldsY[wv];

    const long rowBase = (long)(blockIdx.x * 4 + wv) * tiles_per_wave * 16;
    const float* xrow = x + (rowBase + c) * (long)IN_DIM;

    float4 xa, xb, xct;
    {
        const float* p = xrow + q * 8;
        xa = *(const float4*)p;
        xb = *(const float4*)(p + 4);
        xct = (q == 0) ? *(const float4*)(xrow + 32) : make_float4(0.f, 0.f, 0.f, 0.f);
    }

    __syncthreads();                               // weights resident in LDS
    const char* Wb = (const char*)ldsW;

#pragma unroll 1
    for (int tile = 0; tile < tiles_per_wave; ++tile) {
        float4 na = xa, nb = xb, nc2 = xct;
        if (tile + 1 < tiles_per_wave) {
            const float* p = xrow + (size_t)(tile + 1) * 16 * IN_DIM + q * 8;
            na = *(const float4*)p;
            nb = *(const float4*)(p + 4);
            if (q == 0) nc2 = *(const float4*)(xrow + (size_t)(tile + 1) * 16 * IN_DIM + 32);
        }

        // B-operand from x, packed with v_cvt_pkrtz (2 floats/op); bit_cast keeps
        // everything in registers (unions here caused scratch spills in R6).
        float4 t0, t1;
        t0.x = pk2f(xa.x, xa.y);
        t0.y = pk2f(xa.z, xa.w);
        t0.z = pk2f(xb.x, xb.y);
        t0.w = pk2f(xb.z, xb.w);
        t1.x = pk2f(xct.x, xct.y);                  // xct already 0 for q!=0
        t1.y = pk2f(xct.z, xct.w);
        t1.z = (q == 0) ? pk2f(1.0f, 0.0f) : 0.0f;  // ghost feature -> bias
        t1.w = 0.0f;
        const half8 Bx0 = __builtin_bit_cast(half8, t0);
        const half8 Bx1 = __builtin_bit_cast(half8, t1);

        // ---- tiles 8 (B/C interleaved) and 9 (dt duplicated) first ----
        floatx4 acc8, acc9;
        {
            const half8 c80 = *(const half8*)(Wb + (size_t)(16 * 64 + lane) * 16);
            const half8 c81 = *(const half8*)(Wb + (size_t)(17 * 64 + lane) * 16);
            const half8 c90 = *(const half8*)(Wb + (size_t)(18 * 64 + lane) * 16);
            const half8 c91 = *(const half8*)(Wb + (size_t)(19 * 64 + lane) * 16);
            floatx4 z4 = {0.f, 0.f, 0.f, 0.f};
            acc8 = __builtin_amdgcn_mfma_f32_16x16x32_f16(c80, Bx0, z4, 0, 0, 0);
            acc8 = __builtin_amdgcn_mfma_f32_16x16x32_f16(c81, Bx1, acc8, 0, 0, 0);
            acc9 = __builtin_amdgcn_mfma_f32_16x16x32_f16(c90, Bx0, z4, 0, 0, 0);
            acc9 = __builtin_amdgcn_mfma_f32_16x16x32_f16(c91, Bx1, acc9, 0, 0, 0);
        }

        // bc: in-lane silu(B[s])*silu(C[s]) pairs (s = 2q + {0,1}), then
        // xor16 + xor32 sum over the 4 q-lanes -> bc in ALL lanes. 2 shuffles.
        float part;
        {
            const float b0 = acc8[0], c0 = acc8[1], b1 = acc8[2], c1 = acc8[3];
            const float d0 = (1.0f + __expf(-b0)) * (1.0f + __expf(-c0));
            const float d1 = (1.0f + __expf(-b1)) * (1.0f + __expf(-c1));
            part = b0 * c0 * fast_rcp(d0) + b1 * c1 * fast_rcp(d1);
        }
        const float h1 = part + __shfl_xor(part, 16, 64);
        const float bc = h1 + __shfl_xor(h1, 32, 64);

        // per-head scale, fully lane-local: acc9[t] = dt for head 2t+hb
        float sclA[4];
#pragma unroll
        for (int t = 0; t < 4; ++t)
            sclA[t] = __builtin_fmaf(softplus_f(acc9[t]), bc, dsk[t]);

        // ---- z/xh pairs: compute 4 MFMAs, consume immediately, discard ----
        // y = silu(xh_conv)*scale*silu(z); two rcps fused into one; pack to
        // fp16 as produced (yp, 8 regs). Only 16 acc regs live at any point.
        floatx2 yp[4];
        float ssum = 0.f;
#pragma unroll
        for (int t = 0; t < 4; ++t) {
            const half8 cz0 = *(const half8*)(Wb + (size_t)((t * 2 + 0) * 64 + lane) * 16);
            const half8 cz1 = *(const half8*)(Wb + (size_t)((t * 2 + 1) * 64 + lane) * 16);
            const half8 cx0 = *(const half8*)(Wb + (size_t)(((t + 4) * 2 + 0) * 64 + lane) * 16);
            const half8 cx1 = *(const half8*)(Wb + (size_t)(((t + 4) * 2 + 1) * 64 + lane) * 16);
            floatx4 z4 = {0.f, 0.f, 0.f, 0.f};
            floatx4 az = __builtin_amdgcn_mfma_f32_16x16x32_f16(cz0, Bx0, z4, 0, 0, 0);
            az = __builtin_amdgcn_mfma_f32_16x16x32_f16(cz1, Bx1, az, 0, 0, 0);
            floatx4 ax = __builtin_amdgcn_mfma_f32_16x16x32_f16(cx0, Bx0, z4, 0, 0, 0);
            ax = __builtin_amdgcn_mfma_f32_16x16x32_f16(cx1, Bx1, ax, 0, 0, 0);

            float v[4];
#pragma unroll
            for (int r = 0; r < 4; ++r) {
                const float zr = az[r], xh = ax[r];
                const float den = (1.0f + __expf(-zr)) * (1.0f + __expf(-xh));
                v[r] = zr * xh * sclA[t] * fast_rcp(den);
                ssum = __builtin_fmaf(v[r], v[r], ssum);
            }
            yp[t].x = pk2f(v[0], v[1]);
            yp[t].y = pk2f(v[2], v[3]);
        }
        ssum += __shfl_xor(ssum, 16, 64);
        ssum += __shfl_xor(ssum, 32, 64);
        const float rs = __builtin_amdgcn_rsqf(__builtin_fmaf(ssum, 1.0f / 64.0f, 1e-5f));

        // y -> LDS (half, stride 72) -> B-operand for GEMM2
#pragma unroll
        for (int t = 0; t < 4; ++t)
            *(floatx2*)(myL + c * 72 + 16 * t + 4 * q) = yp[t];   // 8B-aligned
        half8 By0 = *(const half8*)(myL + c * 72 + 8 * q);
        half8 By1 = *(const half8*)(myL + c * 72 + 32 + 8 * q);

        // GEMM2 A-fragments loaded right before use
        const half8 A300 = *(const half8*)(Wb + (size_t)(20 * 64 + lane) * 16);
        const half8 A301 = *(const half8*)(Wb + (size_t)(21 * 64 + lane) * 16);
        const half8 A310 = *(const half8*)(Wb + (size_t)(22 * 64 + lane) * 16);
        const half8 A311 = *(const half8*)(Wb + (size_t)(23 * 64 + lane) * 16);

        // GEMM2 transposed: logits^T; lane (c,q) reg r = out-ch {4q+r, 16+4q+r}, row c
        floatx4 z4 = {0.f, 0.f, 0.f, 0.f};
        floatx4 lg0 = __builtin_amdgcn_mfma_f32_16x16x32_f16(A300, By0, z4, 0, 0, 0);
        lg0 = __builtin_amdgcn_mfma_f32_16x16x32_f16(A301, By1, lg0, 0, 0, 0);
        floatx4 lg1 = __builtin_amdgcn_mfma_f32_16x16x32_f16(A310, By0, z4, 0, 0, 0);
        lg1 = __builtin_amdgcn_mfma_f32_16x16x32_f16(A311, By1, lg1, 0, 0, 0);

        // softmax over 32 out-chs; max-pass skipped (|logit*rs| small, fp32-safe);
        // log2e folded into rs so each exp is a single v_exp_f32 after one mul.
        const float rs2 = rs * 1.44269504f;
        float e0[4], e1[4];
        float lsum = 0.f;
#pragma unroll
        for (int r = 0; r < 4; ++r) {
            e0[r] = __builtin_amdgcn_exp2f(lg0[r] * rs2);
            e1[r] = __builtin_amdgcn_exp2f(lg1[r] * rs2);
            lsum += e0[r] + e1[r];
        }
        lsum += __shfl_xor(lsum, 16, 64);
        lsum += __shfl_xor(lsum, 32, 64);
        const float inv = fast_rcp(lsum);

        const long orow = rowBase + (long)tile * 16 + c;
        *(float4*)(out + orow * 32 + 4 * q) =
            make_float4(e0[0] * inv, e0[1] * inv, e0[2] * inv, e0[3] * inv);
        *(float4*)(out + orow * 32 + 16 + 4 * q) =
            make_float4(e1[0] * inv, e1[1] * inv, e1[2] * inv, e1[3] * inv);

        xa = na; xb = nb; xct = nc2;
    }
}

extern "C" void kernel_launch(void* const* d_in, const int* in_sizes, int n_in,
                              void* d_out, int out_size, void* d_ws, size_t ws_size,
                              hipStream_t stream) {
    const float* x          = (const float*)d_in[0];
    const float* f_out_w    = (const float*)d_in[1];
    const float* f_out_b    = (const float*)d_in[2];
    const float* in_proj_w  = (const float*)d_in[3];
    const float* conv_w     = (const float*)d_in[4];
    const float* conv_b     = (const float*)d_in[5];
    const float* dt_bias    = (const float*)d_in[6];
    // d_in[7] = A_log — unused by the reference
    const float* D_skip     = (const float*)d_in[8];
    const float* norm_w     = (const float*)d_in[9];
    const float* out_proj_w = (const float*)d_in[10];
    float* out = (float*)d_out;

    const int n = in_sizes[0] / IN_DIM;                 // 524288
    const int tiles_per_wave = n / (BLOCKS * 4 * 16);   // 4

    hipLaunchKernelGGL(prep_kernel, dim3(24), dim3(64), 0, stream,
                       f_out_w, f_out_b, in_proj_w, conv_w, conv_b, dt_bias,
                       norm_w, out_proj_w, d_ws);
    hipLaunchKernelGGL(mamba_mfma_kernel, dim3(BLOCKS), dim3(256), 0, stream,
                       x, D_skip, d_ws, out, tiles_per_wave);
}

// Round 9
// 156.422 us; speedup vs baseline: 1.6292x; 1.0009x over previous
//
#include <hip/hip_runtime.h>
#include <math.h>

typedef _Float16 half8 __attribute__((ext_vector_type(8)));
typedef __fp16 fp16x2 __attribute__((ext_vector_type(2)));
typedef float floatx4 __attribute__((ext_vector_type(4)));
typedef float floatx2 __attribute__((ext_vector_type(2)));

constexpr int IN_DIM = 36;
constexpr int BLOCKS = 2048;
// R16 channel map (prep-side remaps; zxbcdt source channels):
//   z-tile u (fid 2u):   tile-row c = z ch  8*(c>>2) + 4*(u&1) + (c&3) + 32*(u>>1)
//   xh-tile u (fid 8+2u): same + 64
//   => after GEMM1, lane (c,q) holds y chs {8q..8q+7} (t=0,1) and
//      {32+8q..+7} (t=2,3)  ==  GEMM2 By0/By1 IN REGISTER (no LDS hop).
//      Head of every ch in tile t for lane q: q + 4*(t>=2).
//   tile 8 (B/C interleave, R15): row c = ((c&1)?136:128) + 2*(c>>2) + ((c>>1)&1)
//   tile 9 (dt):          row c = 144 + (c>>2) + 4*((c&3)>>1)
//      => lane q: acc9[0] = dt head q, acc9[2] = dt head q+4.

__device__ __forceinline__ float fast_rcp(float v) { return __builtin_amdgcn_rcpf(v); }
__device__ __forceinline__ float silu_f(float v) { return v * fast_rcp(1.0f + __expf(-v)); }
__device__ __forceinline__ float softplus_f(float v) {
    return fmaxf(v, 0.0f) + __logf(1.0f + __expf(-fabsf(v)));
}
__device__ __forceinline__ float pk2f(float a, float b) {
    fp16x2 p = __builtin_amdgcn_cvt_pkrtz(a, b);   // v_cvt_pkrtz_f16_f32
    return __builtin_bit_cast(float, p);
}

// ---- prep: 24 fp16 A-operand fragments into d_ws (one block per fragment) ----
// fid 0..19: GEMM1 A = Wc^T (Wc[k][ch] = sum_m f_out_w[m][k]*in_proj_w[ch][m],
//   conv_w folded for ch in [64,144)). Ghost k=36 carries the fully-fused bias.
// fid 20..23: GEMM2 A = out_proj_w[m][k] * norm_w[k] (norm fold).
extern "C" __global__ void __launch_bounds__(64)
prep_kernel(const float* __restrict__ f_out_w, const float* __restrict__ f_out_b,
            const float* __restrict__ in_proj_w, const float* __restrict__ conv_w,
            const float* __restrict__ conv_b, const float* __restrict__ dt_bias,
            const float* __restrict__ norm_w, const float* __restrict__ out_proj_w,
            void* __restrict__ ws) {
    const int fid = blockIdx.x;
    const int L = threadIdx.x;
    const int c = L & 15, q = L >> 4;
    unsigned short* fr = (unsigned short*)ws;
    for (int j = 0; j < 8; ++j) {
        float val = 0.f;
        if (fid < 20) {
            const int t = fid >> 1, ks = fid & 1;
            int m;
            if (t < 8) {                            // z (t<4) / xh (t>=4) remap
                const int u = t & 3;
                m = ((t < 4) ? 0 : 64) +
                    8 * (c >> 2) + 4 * (u & 1) + (c & 3) + 32 * (u >> 1);
            } else if (t == 8) {                    // B/C interleave remap (R15)
                m = ((c & 1) ? 136 : 128) + 2 * (c >> 2) + ((c >> 1) & 1);
            } else {                                // dt: heads {Q, Q+4} per lane
                m = 144 + (c >> 2) + 4 * ((c & 3) >> 1);
            }
            const int k = ks * 32 + q * 8 + j;      // feature
            if (m < 152) {
                if (k < IN_DIM) {
                    float acc = 0.f;
                    for (int mm = 0; mm < 32; ++mm)
                        acc += f_out_w[mm * IN_DIM + k] * in_proj_w[m * 32 + mm];
                    if (m >= 64 && m < 144) acc *= conv_w[(m - 64) * 2 + 1];
                    val = acc;
                } else if (k == IN_DIM) {           // ghost-feature bias slot
                    float acc = 0.f;
                    for (int mm = 0; mm < 32; ++mm)
                        acc += f_out_b[mm] * in_proj_w[m * 32 + mm];
                    if (m >= 64 && m < 144)      val = acc * conv_w[(m - 64) * 2 + 1] + conv_b[m - 64];
                    else if (m >= 144)           val = acc + dt_bias[m - 144];
                    else                         val = acc;
                }
            }
        } else {
            const int mt = (fid - 20) >> 1, ks = (fid - 20) & 1;
            const int m = mt * 16 + c;              // out channel (<32)
            const int k = ks * 32 + q * 8 + j;      // y channel (<64)
            val = out_proj_w[m * 64 + k] * norm_w[k];
        }
        _Float16 h = (_Float16)val;
        fr[fid * 512 + L * 8 + j] = __builtin_bit_cast(unsigned short, h);
    }
}

// ---- main: transposed GEMMs; lane (c,q) owns row c of its 16-row tile ----
// R16 = R15 (lane-local bc/scale; 45.4us) + y-in-register GEMM2: the z/xh
// channel remap (see map above) makes GEMM1's output land EXACTLY in GEMM2's
// B-operand fragment layout, deleting the y->LDS->By round-trip (4 ds_write +
// 2 ds_read_b128 + 2 waitcnts of serial latency per tile) and ldsY itself.
// Same remap makes each lane's heads {q, q+4}: 2 softplus instead of 4, and
// GEMM2 no longer depends on the ssum shuffle chain (they overlap).
// No new live state (spill cliff respected — R10/R12/R14 lesson).
extern "C" __global__ void __launch_bounds__(256, 3)
mamba_mfma_kernel(const float* __restrict__ x,
                  const float* __restrict__ D_skip,
                  const void* __restrict__ ws,
                  float* __restrict__ out,
                  int tiles_per_wave) {
    __shared__ float4 ldsW[1536];                  // 24 KiB: 24 A-fragments, 16B-aligned
    const int lane = threadIdx.x & 63;
    const int wv   = threadIdx.x >> 6;
    const int c = lane & 15, q = lane >> 4;

    // cooperative stage of all 24 fragments: 24576 B / 256 thr = 6 float4 each
    {
        const float4* src = (const float4*)ws;
#pragma unroll
        for (int i = 0; i < 6; ++i)
            ldsW[threadIdx.x + 256 * i] = src[threadIdx.x + 256 * i];
    }

    // D_skip for this lane's two heads (q and q+4)
    const float dsk0 = D_skip[q];
    const float dsk1 = D_skip[q + 4];

    const long rowBase = (long)(blockIdx.x * 4 + wv) * tiles_per_wave * 16;
    const float* xrow = x + (rowBase + c) * (long)IN_DIM;

    float4 xa, xb, xct;
    {
        const float* p = xrow + q * 8;
        xa = *(const float4*)p;
        xb = *(const float4*)(p + 4);
        xct = (q == 0) ? *(const float4*)(xrow + 32) : make_float4(0.f, 0.f, 0.f, 0.f);
    }

    __syncthreads();                               // weights resident in LDS
    const char* Wb = (const char*)ldsW;

#pragma unroll 1
    for (int tile = 0; tile < tiles_per_wave; ++tile) {
        float4 na = xa, nb = xb, nc2 = xct;
        if (tile + 1 < tiles_per_wave) {
            const float* p = xrow + (size_t)(tile + 1) * 16 * IN_DIM + q * 8;
            na = *(const float4*)p;
            nb = *(const float4*)(p + 4);
            if (q == 0) nc2 = *(const float4*)(xrow + (size_t)(tile + 1) * 16 * IN_DIM + 32);
        }

        // B-operand from x, packed with v_cvt_pkrtz (2 floats/op); bit_cast keeps
        // everything in registers (unions here caused scratch spills in R6).
        float4 t0, t1;
        t0.x = pk2f(xa.x, xa.y);
        t0.y = pk2f(xa.z, xa.w);
        t0.z = pk2f(xb.x, xb.y);
        t0.w = pk2f(xb.z, xb.w);
        t1.x = pk2f(xct.x, xct.y);                  // xct already 0 for q!=0
        t1.y = pk2f(xct.z, xct.w);
        t1.z = (q == 0) ? pk2f(1.0f, 0.0f) : 0.0f;  // ghost feature -> bias
        t1.w = 0.0f;
        const half8 Bx0 = __builtin_bit_cast(half8, t0);
        const half8 Bx1 = __builtin_bit_cast(half8, t1);

        // ---- tiles 8 (B/C interleaved) and 9 (dt remapped) first ----
        floatx4 acc8, acc9;
        {
            const half8 c80 = *(const half8*)(Wb + (size_t)(16 * 64 + lane) * 16);
            const half8 c81 = *(const half8*)(Wb + (size_t)(17 * 64 + lane) * 16);
            const half8 c90 = *(const half8*)(Wb + (size_t)(18 * 64 + lane) * 16);
            const half8 c91 = *(const half8*)(Wb + (size_t)(19 * 64 + lane) * 16);
            floatx4 z4 = {0.f, 0.f, 0.f, 0.f};
            acc8 = __builtin_amdgcn_mfma_f32_16x16x32_f16(c80, Bx0, z4, 0, 0, 0);
            acc8 = __builtin_amdgcn_mfma_f32_16x16x32_f16(c81, Bx1, acc8, 0, 0, 0);
            acc9 = __builtin_amdgcn_mfma_f32_16x16x32_f16(c90, Bx0, z4, 0, 0, 0);
            acc9 = __builtin_amdgcn_mfma_f32_16x16x32_f16(c91, Bx1, acc9, 0, 0, 0);
        }

        // bc: in-lane silu(B[s])*silu(C[s]) pairs (s = 2q + {0,1}), then
        // xor16 + xor32 sum over the 4 q-lanes -> bc in ALL lanes. 2 shuffles.
        float part;
        {
            const float b0 = acc8[0], c0 = acc8[1], b1 = acc8[2], c1 = acc8[3];
            const float d0 = (1.0f + __expf(-b0)) * (1.0f + __expf(-c0));
            const float d1 = (1.0f + __expf(-b1)) * (1.0f + __expf(-c1));
            part = b0 * c0 * fast_rcp(d0) + b1 * c1 * fast_rcp(d1);
        }
        const float h1 = part + __shfl_xor(part, 16, 64);
        const float bc = h1 + __shfl_xor(h1, 32, 64);

        // per-head scale, lane-local: acc9[0] = dt head q, acc9[2] = head q+4
        const float sclH0 = __builtin_fmaf(softplus_f(acc9[0]), bc, dsk0);
        const float sclH1 = __builtin_fmaf(softplus_f(acc9[2]), bc, dsk1);

        // ---- z/xh pairs: 4 MFMAs per t, consumed immediately into By ----
        // tile t supplies y chs {8q + 4*(t&1) + r + 32*(t>>1)} (head q+4*(t>>1))
        // -> packed pk2f pairs land DIRECTLY in By0 (t=0,1) / By1 (t=2,3).
        float4 by0f, by1f;
        float ssum = 0.f;
#pragma unroll
        for (int t = 0; t < 4; ++t) {
            const half8 cz0 = *(const half8*)(Wb + (size_t)((t * 2 + 0) * 64 + lane) * 16);
            const half8 cz1 = *(const half8*)(Wb + (size_t)((t * 2 + 1) * 64 + lane) * 16);
            const half8 cx0 = *(const half8*)(Wb + (size_t)(((t + 4) * 2 + 0) * 64 + lane) * 16);
            const half8 cx1 = *(const half8*)(Wb + (size_t)(((t + 4) * 2 + 1) * 64 + lane) * 16);
            floatx4 z4 = {0.f, 0.f, 0.f, 0.f};
            floatx4 az = __builtin_amdgcn_mfma_f32_16x16x32_f16(cz0, Bx0, z4, 0, 0, 0);
            az = __builtin_amdgcn_mfma_f32_16x16x32_f16(cz1, Bx1, az, 0, 0, 0);
            floatx4 ax = __builtin_amdgcn_mfma_f32_16x16x32_f16(cx0, Bx0, z4, 0, 0, 0);
            ax = __builtin_amdgcn_mfma_f32_16x16x32_f16(cx1, Bx1, ax, 0, 0, 0);

            const float scl = (t < 2) ? sclH0 : sclH1;
            float v[4];
#pragma unroll
            for (int r = 0; r < 4; ++r) {
                const float zr = az[r], xh = ax[r];
                const float den = (1.0f + __expf(-zr)) * (1.0f + __expf(-xh));
                v[r] = zr * xh * scl * fast_rcp(den);
                ssum = __builtin_fmaf(v[r], v[r], ssum);
            }
            const float plo = pk2f(v[0], v[1]);
            const float phi = pk2f(v[2], v[3]);
            if (t == 0)      { by0f.x = plo; by0f.y = phi; }
            else if (t == 1) { by0f.z = plo; by0f.w = phi; }
            else if (t == 2) { by1f.x = plo; by1f.y = phi; }
            else             { by1f.z = plo; by1f.w = phi; }
        }
        const half8 By0 = __builtin_bit_cast(half8, by0f);
        const half8 By1 = __builtin_bit_cast(half8, by1f);

        // GEMM2 A-fragments (weights) + MFMAs — independent of the ssum chain,
        // so they overlap the reduction shuffles below.
        const half8 A300 = *(const half8*)(Wb + (size_t)(20 * 64 + lane) * 16);
        const half8 A301 = *(const half8*)(Wb + (size_t)(21 * 64 + lane) * 16);
        const half8 A310 = *(const half8*)(Wb + (size_t)(22 * 64 + lane) * 16);
        const half8 A311 = *(const half8*)(Wb + (size_t)(23 * 64 + lane) * 16);

        floatx4 z4 = {0.f, 0.f, 0.f, 0.f};
        floatx4 lg0 = __builtin_amdgcn_mfma_f32_16x16x32_f16(A300, By0, z4, 0, 0, 0);
        lg0 = __builtin_amdgcn_mfma_f32_16x16x32_f16(A301, By1, lg0, 0, 0, 0);
        floatx4 lg1 = __builtin_amdgcn_mfma_f32_16x16x32_f16(A310, By0, z4, 0, 0, 0);
        lg1 = __builtin_amdgcn_mfma_f32_16x16x32_f16(A311, By1, lg1, 0, 0, 0);

        float ssr = ssum + __shfl_xor(ssum, 16, 64);
        ssr += __shfl_xor(ssr, 32, 64);
        const float rs = __builtin_amdgcn_rsqf(__builtin_fmaf(ssr, 1.0f / 64.0f, 1e-5f));

        // softmax over 32 out-chs; max-pass skipped (|logit*rs| small, fp32-safe);
        // log2e folded into rs so each exp is a single v_exp_f32 after one mul.
        const float rs2 = rs * 1.44269504f;
        float e0[4], e1[4];
        float lsum = 0.f;
#pragma unroll
        for (int r = 0; r < 4; ++r) {
            e0[r] = __builtin_amdgcn_exp2f(lg0[r] * rs2);
            e1[r] = __builtin_amdgcn_exp2f(lg1[r] * rs2);
            lsum += e0[r] + e1[r];
        }
        lsum += __shfl_xor(lsum, 16, 64);
        lsum += __shfl_xor(lsum, 32, 64);
        const float inv = fast_rcp(lsum);

        const long orow = rowBase + (long)tile * 16 + c;
        *(float4*)(out + orow * 32 + 4 * q) =
            make_float4(e0[0] * inv, e0[1] * inv, e0[2] * inv, e0[3] * inv);
        *(float4*)(out + orow * 32 + 16 + 4 * q) =
            make_float4(e1[0] * inv, e1[1] * inv, e1[2] * inv, e1[3] * inv);

        xa = na; xb = nb; xct = nc2;
    }
}

extern "C" void kernel_launch(void* const* d_in, const int* in_sizes, int n_in,
                              void* d_out, int out_size, void* d_ws, size_t ws_size,
                              hipStream_t stream) {
    const float* x          = (const float*)d_in[0];
    const float* f_out_w    = (const float*)d_in[1];
    const float* f_out_b    = (const float*)d_in[2];
    const float* in_proj_w  = (const float*)d_in[3];
    const float* conv_w     = (const float*)d_in[4];
    const float* conv_b     = (const float*)d_in[5];
    const float* dt_bias    = (const float*)d_in[6];
    // d_in[7] = A_log — unused by the reference
    const float* D_skip     = (const float*)d_in[8];
    const float* norm_w     = (const float*)d_in[9];
    const float* out_proj_w = (const float*)d_in[10];
    float* out = (float*)d_out;

    const int n = in_sizes[0] / IN_DIM;                 // 524288
    const int tiles_per_wave = n / (BLOCKS * 4 * 16);   // 4

    hipLaunchKernelGGL(prep_kernel, dim3(24), dim3(64), 0, stream,
                       f_out_w, f_out_b, in_proj_w, conv_w, conv_b, dt_bias,
                       norm_w, out_proj_w, d_ws);
    hipLaunchKernelGGL(mamba_mfma_kernel, dim3(BLOCKS), dim3(256), 0, stream,
                       x, D_skip, d_ws, out, tiles_per_wave);
}